// Round 17
// baseline (52.543 us; speedup 1.0000x reference)
//
#include <hip/hip_runtime.h>
#include <hip/hip_bf16.h>
#include <hip/hip_fp16.h>

typedef unsigned int uint;
typedef unsigned short ushort;
typedef __attribute__((ext_vector_type(4))) float f32x4;
typedef __attribute__((ext_vector_type(8))) _Float16 f16x8;

// async global->LDS, 16B per lane; LDS dest is wave-uniform-base + lane*16 (linear)
#define LDS16(gp, lp)                                                                    \
  __builtin_amdgcn_global_load_lds((const __attribute__((address_space(1))) uint*)(gp),  \
                                   (__attribute__((address_space(3))) uint*)(lp), 16, 0, 0)

// pack two f32 -> one u32 of two f16 (RTZ)
__device__ __forceinline__ uint pk_f16(float a, float b) {
  __fp16 __attribute__((ext_vector_type(2))) r = __builtin_amdgcn_cvt_pkrtz(a, b);
  union { decltype(r) v; uint u; } c;
  c.v = r;
  return c.u;
}

// ---------------------------------------------------------------------------
// Kernel 1: W (1024x511 f32, row-major) -> transposed f16 [512][1024],
// col 511 zero-padded. LDS 64x65 tile transpose keeps both sides coalesced.
// ---------------------------------------------------------------------------
__global__ __launch_bounds__(256) void prep_w(const float* __restrict__ W,
                                              _Float16* __restrict__ WT) {
  __shared__ float t[64][65];
  const int tid = threadIdx.x;
  const int k0 = (blockIdx.x >> 3) * 64;
  const int n0 = (blockIdx.x & 7) * 64;
#pragma unroll
  for (int i = 0; i < 16; ++i) {
    int idx = i * 256 + tid;
    int kk = idx >> 6, nn = idx & 63;
    int n = n0 + nn;
    t[kk][nn] = (n < 511) ? W[(size_t)(k0 + kk) * 511 + n] : 0.f;
  }
  __syncthreads();
#pragma unroll
  for (int i = 0; i < 16; ++i) {
    int idx = i * 256 + tid;
    int nn = idx >> 6, kk = idx & 63;
    WT[(size_t)(n0 + nn) * 1024 + k0 + kk] = (_Float16)t[kk][nn];
  }
}

// ---------------------------------------------------------------------------
// Kernel 2: P = sigmoid(X @ W + b), f16 [16384][512] (col 511 junk).
// BYTE-MINIMAL geometry: 128 x 256 tile, grid 256 (1 block/CU).
// Total staged = B 128MB + A 131MB = 262MB (vs 320MB at BM=64/BN=512):
// at the measured ~13.5 B/cyc/CU supply wall this is the only remaining lever.
// 1024 threads (16 waves 4Mx4N, wave tile 32x64), BK=64, 16 phases.
// r13-proven skeleton: counted vmcnt(2), A reg-staged f32->f16, B DMA,
// both-side XOR swizzles, raw s_barrier pairs.
// ---------------------------------------------------------------------------
__global__ __launch_bounds__(1024, 1) void gemm_sig(const float* __restrict__ X,
                                                    const _Float16* __restrict__ WT,
                                                    const float* __restrict__ bvec,
                                                    __half* __restrict__ P) {
  __shared__ _Float16 ldsB[2][256 * 64];  // 2 x 32 KB
  __shared__ _Float16 ldsA[2][128 * 64];  // 2 x 16 KB   (total 96 KB -> 1 block/CU)

  const int tid = threadIdx.x;            // 0..1023
  const int lane = tid & 63;
  const int w = tid >> 6;                 // 0..15
  const int wm = w >> 2, wn = w & 3;      // 4(M) x 4(N)
  const int l16 = lane & 15;
  const int g = lane >> 4;

  // XCD-chunked swizzle (256 blocks, 8 XCDs, bijective)
  const int bid = blockIdx.x;
  const int swz = (bid & 7) * 32 + (bid >> 3);
  const int rbase = (swz >> 1) * 128;
  const int nbase = (swz & 1) * 256;

  // A staging: row = tid>>3 (0..127), 8 consecutive f32 per thread
  const int arow = tid >> 3;
  const int aseg = tid & 7;
  const float* aSrc = X + (size_t)(rbase + arow) * 1024 + aseg * 8;
  const int awOff = arow * 64 + (aseg ^ (arow & 7)) * 8;  // swizzled 16B slot

  f32x4 acc[2][4];
#pragma unroll
  for (int i = 0; i < 2; ++i)
#pragma unroll
    for (int j = 0; j < 4; ++j) acc[i][j] = (f32x4)0.f;

  f32x4 aReg[2];

  auto issueA = [&](int kt) {
    const float* s = aSrc + kt * 64;
    aReg[0] = *(const f32x4*)(s);
    aReg[1] = *(const f32x4*)(s + 4);
  };

  auto writeA = [&](int buf) {
    union { uint u[4]; f16x8 v; } c;
    c.u[0] = pk_f16(aReg[0][0], aReg[0][1]);
    c.u[1] = pk_f16(aReg[0][2], aReg[0][3]);
    c.u[2] = pk_f16(aReg[1][0], aReg[1][1]);
    c.u[3] = pk_f16(aReg[1][2], aReg[1][3]);
    *(f16x8*)&ldsA[buf][awOff] = c.v;
  };

  auto issueB = [&](int buf, int kt) {  // 2 x global_load_lds, pre-swizzled src
#pragma unroll
    for (int i = 0; i < 2; ++i) {
      int l = tid + 1024 * i;           // 0..2047 16B slots
      int c = l >> 3, gp = l & 7;
      int gs = gp ^ (c & 7);
      LDS16(WT + (size_t)(nbase + c) * 1024 + kt * 64 + gs * 8, &ldsB[buf][l * 8]);
    }
  };

  auto compute = [&](int buf) {
#pragma unroll
    for (int kk = 0; kk < 2; ++kk) {
      f16x8 b[4], a[2];
#pragma unroll
      for (int ni = 0; ni < 4; ++ni) {
        int c = wn * 64 + ni * 16 + l16;
        b[ni] = *(const f16x8*)&ldsB[buf][c * 64 + (((kk * 4 + g) ^ (c & 7)) * 8)];
      }
#pragma unroll
      for (int mi = 0; mi < 2; ++mi) {
        int r = wm * 32 + mi * 16 + l16;
        a[mi] = *(const f16x8*)&ldsA[buf][r * 64 + (((kk * 4 + g) ^ (r & 7)) * 8)];
      }
      __builtin_amdgcn_s_setprio(1);
#pragma unroll
      for (int mi = 0; mi < 2; ++mi)
#pragma unroll
        for (int ni = 0; ni < 4; ++ni)
          acc[mi][ni] = __builtin_amdgcn_mfma_f32_16x16x32_f16(a[mi], b[ni], acc[mi][ni], 0, 0, 0);
      __builtin_amdgcn_s_setprio(0);
    }
  };

  // prologue: B(0)[2], A(0)[2], B(1)[2] in flight
  issueB(0, 0);
  issueA(0);
  issueB(1, 1);

#pragma unroll
  for (int t = 0; t < 16; ++t) {
    const int buf = t & 1;
    if (t < 15) {
      asm volatile("s_waitcnt vmcnt(2)" ::: "memory");  // A(t)+B(t) landed; B(t+1) flying
    } else {
      asm volatile("s_waitcnt vmcnt(0)" ::: "memory");
    }
    __builtin_amdgcn_sched_barrier(0);
    writeA(buf);
    asm volatile("s_waitcnt lgkmcnt(0)" ::: "memory");
    __builtin_amdgcn_sched_barrier(0);
    __builtin_amdgcn_s_barrier();
    __builtin_amdgcn_sched_barrier(0);
    if (t + 1 < 16) issueA(t + 1);
    __builtin_amdgcn_sched_barrier(0);
    compute(buf);
    __builtin_amdgcn_sched_barrier(0);
    __builtin_amdgcn_s_barrier();                       // all waves done with buf
    if (t + 2 < 16) issueB(buf, t + 2);
  }

  // epilogue: bias + sigmoid, store f16
#pragma unroll
  for (int mi = 0; mi < 2; ++mi) {
#pragma unroll
    for (int ni = 0; ni < 4; ++ni) {
      int gc = nbase + wn * 64 + ni * 16 + l16;
      float bias = (gc < 511) ? bvec[gc] : 0.f;
#pragma unroll
      for (int q = 0; q < 4; ++q) {
        int gr = rbase + wm * 32 + mi * 16 + g * 4 + q;
        float z = acc[mi][ni][q] + bias;
        float pv = 1.f / (1.f + __expf(-z));
        P[(size_t)gr * 512 + gc] = __float2half(pv);
      }
    }
  }
}

// ---------------------------------------------------------------------------
// Kernel 3: tree propagation + leaf matmul (f16 MFMA). r2-proven version:
// 1 block = 16 rows; 4 waves split the 16 t-chunks, partials reduced in LDS.
// ---------------------------------------------------------------------------
__global__ __launch_bounds__(256) void tree_out(const __half* __restrict__ P,
                                                const float* __restrict__ LL,
                                                float* __restrict__ out) {
  __shared__ __half plds[16 * 520];
  __shared__ f32x4 red[4][64];
  const int tid = threadIdx.x;
  const int lane = tid & 63;
  const int wid = tid >> 6;
  const int r = lane & 15;
  const int g = lane >> 4;
  const int rbase = blockIdx.x * 16;

#pragma unroll
  for (int i = 0; i < 4; ++i) {
    int row = wid * 4 + i;
    LDS16(P + (size_t)(rbase + row) * 512 + lane * 8, plds + row * 520 + lane * 8);
  }

  f16x8 bfr[4];
  const int col = r;
#pragma unroll
  for (int tt = 0; tt < 4; ++tt) {
    int t = wid * 4 + tt;
#pragma unroll
    for (int p = 0; p < 8; ++p) {
      int k0 = t * 32 + g * 8 + p;
      bfr[tt][p] = (col < 10) ? (_Float16)LL[k0 * 10 + col] : (_Float16)0.f;
    }
  }

  __syncthreads();

  const __half* prow = &plds[r * 520];
  f32x4 acc = (f32x4)0.f;
#pragma unroll
  for (int tt = 0; tt < 4; ++tt) {
    const int t = wid * 4 + tt;
    const int L0 = g * 8 + 32 * t;
    float pref = 1.f;
#pragma unroll
    for (int k = 0; k < 6; ++k) {
      int node = L0 >> (9 - k);
      int bit = (L0 >> (8 - k)) & 1;
      float pv = __half2float(prow[(1 << k) - 1 + node]);
      pref *= bit ? pv : (1.f - pv);
    }
    float p6 = __half2float(prow[63 + (L0 >> 3)]);
    float p7a = __half2float(prow[127 + (L0 >> 2)]);
    float p7b = __half2float(prow[128 + (L0 >> 2)]);
    float p80 = __half2float(prow[255 + (L0 >> 1)]);
    float p81 = __half2float(prow[256 + (L0 >> 1)]);
    float p82 = __half2float(prow[257 + (L0 >> 1)]);
    float p83 = __half2float(prow[258 + (L0 >> 1)]);
    float u1 = pref * p6, u0 = pref - u1;
    float v01 = u0 * p7a, v00 = u0 - v01;
    float v11 = u1 * p7b, v10 = u1 - v11;
    float pr1 = v00 * p80, pr0 = v00 - pr1;
    float pr3 = v01 * p81, pr2 = v01 - pr3;
    float pr5 = v10 * p82, pr4 = v10 - pr5;
    float pr7 = v11 * p83, pr6 = v11 - pr7;
    f16x8 af;
    af[0] = (_Float16)pr0; af[1] = (_Float16)pr1;
    af[2] = (_Float16)pr2; af[3] = (_Float16)pr3;
    af[4] = (_Float16)pr4; af[5] = (_Float16)pr5;
    af[6] = (_Float16)pr6; af[7] = (_Float16)pr7;
    acc = __builtin_amdgcn_mfma_f32_16x16x32_f16(af, bfr[tt], acc, 0, 0, 0);
  }

  red[wid][lane] = acc;
  __syncthreads();
  if (wid == 0 && col < 10) {
    f32x4 a0 = red[0][lane], a1 = red[1][lane], a2 = red[2][lane], a3 = red[3][lane];
#pragma unroll
    for (int q = 0; q < 4; ++q)
      out[(size_t)(rbase + g * 4 + q) * 10 + col] = a0[q] + a1[q] + a2[q] + a3[q];
  }
}

// ---------------------------------------------------------------------------
extern "C" void kernel_launch(void* const* d_in, const int* in_sizes, int n_in,
                              void* d_out, int out_size, void* d_ws, size_t ws_size,
                              hipStream_t stream) {
  const float* X = (const float*)d_in[0];
  const float* W = (const float*)d_in[1];
  const float* bv = (const float*)d_in[2];
  const float* LL = (const float*)d_in[3];
  float* out = (float*)d_out;

  __half* P = (__half*)d_ws;                                         // 16 MB
  _Float16* WT = (_Float16*)((char*)d_ws + (size_t)16384 * 512 * 2); // 1 MB

  prep_w<<<128, 256, 0, stream>>>(W, WT);
  gemm_sig<<<256, 1024, 0, stream>>>(X, WT, bv, P);
  tree_out<<<1024, 256, 0, stream>>>(P, LL, out);
}

// Round 18
// 49.977 us; speedup vs baseline: 1.0513x; 1.0513x over previous
//
#include <hip/hip_runtime.h>
#include <hip/hip_bf16.h>
#include <hip/hip_fp16.h>

typedef unsigned int uint;
typedef unsigned short ushort;
typedef __attribute__((ext_vector_type(4))) float f32x4;
typedef __attribute__((ext_vector_type(8))) _Float16 f16x8;

// async global->LDS, 16B per lane; LDS dest is wave-uniform-base + lane*16 (linear)
#define LDS16(gp, lp)                                                                    \
  __builtin_amdgcn_global_load_lds((const __attribute__((address_space(1))) uint*)(gp),  \
                                   (__attribute__((address_space(3))) uint*)(lp), 16, 0, 0)

// pack two f32 -> one u32 of two f16 (RTZ)
__device__ __forceinline__ uint pk_f16(float a, float b) {
  __fp16 __attribute__((ext_vector_type(2))) r = __builtin_amdgcn_cvt_pkrtz(a, b);
  union { decltype(r) v; uint u; } c;
  c.v = r;
  return c.u;
}

// ---------------------------------------------------------------------------
// Kernel 1: W (1024x511 f32, row-major) -> transposed f16 [512][1024],
// col 511 zero-padded. LDS 64x65 tile transpose keeps both sides coalesced.
// ---------------------------------------------------------------------------
__global__ __launch_bounds__(256) void prep_w(const float* __restrict__ W,
                                              _Float16* __restrict__ WT) {
  __shared__ float t[64][65];
  const int tid = threadIdx.x;
  const int k0 = (blockIdx.x >> 3) * 64;
  const int n0 = (blockIdx.x & 7) * 64;
#pragma unroll
  for (int i = 0; i < 16; ++i) {
    int idx = i * 256 + tid;
    int kk = idx >> 6, nn = idx & 63;
    int n = n0 + nn;
    t[kk][nn] = (n < 511) ? W[(size_t)(k0 + kk) * 511 + n] : 0.f;
  }
  __syncthreads();
#pragma unroll
  for (int i = 0; i < 16; ++i) {
    int idx = i * 256 + tid;
    int nn = idx >> 6, kk = idx & 63;
    WT[(size_t)(n0 + nn) * 1024 + k0 + kk] = (_Float16)t[kk][nn];
  }
}

// ---------------------------------------------------------------------------
// Kernel 2 (FUSED, r13 + micro-opts): 64 rows x full 512 cols -> 64x10 out.
// GEMM stage: 1024 threads (16 waves 2Mx8N), BK=64, counted vmcnt(4),
// B via global_load_lds (pre-swizzled src), A reg-staged by ALL threads
// (1 dwordx4 + 2 cvt + one 8B ds_write each; no doA divergence).
// Tree stage: sigmoid -> P in LDS (stride 520) -> tree + leaf MFMA -> out.
// ---------------------------------------------------------------------------
__global__ __launch_bounds__(1024, 1) void gemm_tree(const float* __restrict__ X,
                                                     const _Float16* __restrict__ WT,
                                                     const float* __restrict__ bvec,
                                                     const float* __restrict__ LL,
                                                     float* __restrict__ out) {
  __shared__ _Float16 ldsB[2][512 * 64];   // 128 KB; reused as plds+red after K-loop
  __shared__ _Float16 ldsA[2][64 * 64];    // 16 KB

  const int tid = threadIdx.x;            // 0..1023
  const int lane = tid & 63;
  const int w = tid >> 6;                 // 0..15
  const int wr = w >> 3, wc = w & 7;      // 2(M) x 8(N)
  const int l16 = lane & 15;
  const int g = lane >> 4;
  const int rbase = blockIdx.x * 64;

  // A staging: ALL 1024 threads; row = tid>>4, 4 consecutive f32 per thread
  const int arow = tid >> 4;              // 0..63
  const int au = tid & 15;                // 8B half-chunk unit
  const float* aSrc = X + (size_t)(rbase + arow) * 1024 + au * 4;
  // 16B-granular swizzle (matches compute-side reads), half-chunk offset +4
  const int awOff = arow * 64 + (((au >> 1) ^ (arow & 7)) * 8) + (au & 1) * 4;

  f32x4 acc[2][4];
#pragma unroll
  for (int i = 0; i < 2; ++i)
#pragma unroll
    for (int j = 0; j < 4; ++j) acc[i][j] = (f32x4)0.f;

  f32x4 aReg;

  auto issueA = [&](int kt) { aReg = *(const f32x4*)(aSrc + kt * 64); };

  auto writeA = [&](int buf) {
    uint2 v;
    v.x = pk_f16(aReg[0], aReg[1]);
    v.y = pk_f16(aReg[2], aReg[3]);
    *(uint2*)&ldsA[buf][awOff] = v;
  };

  auto issueB = [&](int buf, int kt) {  // 4 x global_load_lds, pre-swizzled src
#pragma unroll
    for (int i = 0; i < 4; ++i) {
      int l = tid + 1024 * i;
      int c = l >> 3, gp = l & 7;
      int gs = gp ^ (c & 7);
      LDS16(WT + (size_t)c * 1024 + kt * 64 + gs * 8, &ldsB[buf][l * 8]);
    }
  };

  auto compute = [&](int buf) {
#pragma unroll
    for (int kk = 0; kk < 2; ++kk) {
      f16x8 b[4], a[2];
#pragma unroll
      for (int ni = 0; ni < 4; ++ni) {
        int c = wc * 64 + ni * 16 + l16;
        b[ni] = *(const f16x8*)&ldsB[buf][c * 64 + (((kk * 4 + g) ^ (c & 7)) * 8)];
      }
#pragma unroll
      for (int mi = 0; mi < 2; ++mi) {
        int r = wr * 32 + mi * 16 + l16;
        a[mi] = *(const f16x8*)&ldsA[buf][r * 64 + (((kk * 4 + g) ^ (r & 7)) * 8)];
      }
      __builtin_amdgcn_s_setprio(1);
#pragma unroll
      for (int mi = 0; mi < 2; ++mi)
#pragma unroll
        for (int ni = 0; ni < 4; ++ni)
          acc[mi][ni] = __builtin_amdgcn_mfma_f32_16x16x32_f16(a[mi], b[ni], acc[mi][ni], 0, 0, 0);
      __builtin_amdgcn_s_setprio(0);
    }
  };

  // prologue: B(0)[4], A(0)[1], B(1)[4] in flight (9 total)
  issueB(0, 0);
  issueA(0);
  issueB(1, 1);

#pragma unroll
  for (int t = 0; t < 16; ++t) {
    const int buf = t & 1;
    if (t < 15) {
      asm volatile("s_waitcnt vmcnt(4)" ::: "memory");  // drains B(t)+A(t); B(t+1) flying
    } else {
      asm volatile("s_waitcnt vmcnt(0)" ::: "memory");
    }
    __builtin_amdgcn_sched_barrier(0);
    writeA(buf);
    asm volatile("s_waitcnt lgkmcnt(0)" ::: "memory");
    __builtin_amdgcn_sched_barrier(0);
    __builtin_amdgcn_s_barrier();
    __builtin_amdgcn_sched_barrier(0);
    if (t + 1 < 16) issueA(t + 1);
    __builtin_amdgcn_sched_barrier(0);
    compute(buf);
    __builtin_amdgcn_sched_barrier(0);
    __builtin_amdgcn_s_barrier();                  // all waves done with buf
    if (t + 2 < 16) issueB(buf, t + 2);
  }

  // ---- stage 2a: sigmoid -> P in LDS (padded stride 520) ----
  __half* plds = (__half*)&ldsB[0][0];                       // 64 x 520 = 66.5 KB
  f32x4* red = (f32x4*)((char*)&ldsB[0][0] + 68 * 1024);     // [4 rg][3][64] = 12 KB
#pragma unroll
  for (int mi = 0; mi < 2; ++mi) {
#pragma unroll
    for (int ni = 0; ni < 4; ++ni) {
      int gc = wc * 64 + ni * 16 + l16;
      float bias = (gc < 511) ? bvec[gc] : 0.f;
#pragma unroll
      for (int q = 0; q < 4; ++q) {
        int lr = wr * 32 + mi * 16 + g * 4 + q;   // local row 0..63
        float z = acc[mi][ni][q] + bias;
        float pv = 1.f / (1.f + __expf(-z));
        plds[lr * 520 + gc] = __float2half(pv);
      }
    }
  }
  __syncthreads();

  // ---- stage 2b: tree propagation + leaf MFMA ----
  const int rg = w >> 2, tw = w & 3;
  const int r = lane & 15;   // row within group; also LL col
  const int col = r;

  f16x8 bfr[4];
#pragma unroll
  for (int tt = 0; tt < 4; ++tt) {
    int t = tw * 4 + tt;
#pragma unroll
    for (int p = 0; p < 8; ++p) {
      int k0 = t * 32 + g * 8 + p;
      bfr[tt][p] = (col < 10) ? (_Float16)LL[k0 * 10 + col] : (_Float16)0.f;
    }
  }

  const __half* prow = &plds[(rg * 16 + r) * 520];
  f32x4 tacc = (f32x4)0.f;
#pragma unroll
  for (int tt = 0; tt < 4; ++tt) {
    const int t = tw * 4 + tt;
    const int L0 = g * 8 + 32 * t;
    float pref = 1.f;
#pragma unroll
    for (int k = 0; k < 6; ++k) {
      int node = L0 >> (9 - k);
      int bit = (L0 >> (8 - k)) & 1;
      float pv = __half2float(prow[(1 << k) - 1 + node]);
      pref *= bit ? pv : (1.f - pv);
    }
    float p6 = __half2float(prow[63 + (L0 >> 3)]);
    float p7a = __half2float(prow[127 + (L0 >> 2)]);
    float p7b = __half2float(prow[128 + (L0 >> 2)]);
    float p80 = __half2float(prow[255 + (L0 >> 1)]);
    float p81 = __half2float(prow[256 + (L0 >> 1)]);
    float p82 = __half2float(prow[257 + (L0 >> 1)]);
    float p83 = __half2float(prow[258 + (L0 >> 1)]);
    float u1 = pref * p6, u0 = pref - u1;
    float v01 = u0 * p7a, v00 = u0 - v01;
    float v11 = u1 * p7b, v10 = u1 - v11;
    float pr1 = v00 * p80, pr0 = v00 - pr1;
    float pr3 = v01 * p81, pr2 = v01 - pr3;
    float pr5 = v10 * p82, pr4 = v10 - pr5;
    float pr7 = v11 * p83, pr6 = v11 - pr7;
    f16x8 af;
    af[0] = (_Float16)pr0; af[1] = (_Float16)pr1;
    af[2] = (_Float16)pr2; af[3] = (_Float16)pr3;
    af[4] = (_Float16)pr4; af[5] = (_Float16)pr5;
    af[6] = (_Float16)pr6; af[7] = (_Float16)pr7;
    tacc = __builtin_amdgcn_mfma_f32_16x16x32_f16(af, bfr[tt], tacc, 0, 0, 0);
  }

  if (tw > 0) red[(rg * 3 + (tw - 1)) * 64 + lane] = tacc;
  __syncthreads();

  if (tw == 0 && col < 10) {
    f32x4 a1 = red[(rg * 3 + 0) * 64 + lane];
    f32x4 a2 = red[(rg * 3 + 1) * 64 + lane];
    f32x4 a3 = red[(rg * 3 + 2) * 64 + lane];
#pragma unroll
    for (int q = 0; q < 4; ++q)
      out[(size_t)(rbase + rg * 16 + g * 4 + q) * 10 + col] =
          tacc[q] + a1[q] + a2[q] + a3[q];
  }
}

// ---------------------------------------------------------------------------
extern "C" void kernel_launch(void* const* d_in, const int* in_sizes, int n_in,
                              void* d_out, int out_size, void* d_ws, size_t ws_size,
                              hipStream_t stream) {
  const float* X = (const float*)d_in[0];
  const float* W = (const float*)d_in[1];
  const float* bv = (const float*)d_in[2];
  const float* LL = (const float*)d_in[3];
  float* out = (float*)d_out;

  _Float16* WT = (_Float16*)d_ws;  // 1 MB

  prep_w<<<128, 256, 0, stream>>>(W, WT);
  gemm_tree<<<256, 1024, 0, stream>>>(X, WT, bv, LL, out);
}

// Round 19
// 47.348 us; speedup vs baseline: 1.1097x; 1.0555x over previous
//
#include <hip/hip_runtime.h>
#include <hip/hip_bf16.h>
#include <hip/hip_fp16.h>

typedef unsigned int uint;
typedef unsigned short ushort;
typedef __attribute__((ext_vector_type(4))) float f32x4;
typedef __attribute__((ext_vector_type(8))) _Float16 f16x8;

// async global->LDS, 16B per lane; LDS dest is wave-uniform-base + lane*16 (linear)
#define LDS16(gp, lp)                                                                    \
  __builtin_amdgcn_global_load_lds((const __attribute__((address_space(1))) uint*)(gp),  \
                                   (__attribute__((address_space(3))) uint*)(lp), 16, 0, 0)

// pack two f32 -> one u32 of two f16 (RTZ)
__device__ __forceinline__ uint pk_f16(float a, float b) {
  __fp16 __attribute__((ext_vector_type(2))) r = __builtin_amdgcn_cvt_pkrtz(a, b);
  union { decltype(r) v; uint u; } c;
  c.v = r;
  return c.u;
}

// ---------------------------------------------------------------------------
// Kernel 1: W (1024x511 f32, row-major) -> transposed f16 [512][1024],
// col 511 zero-padded. LDS 64x65 tile transpose keeps both sides coalesced.
// ---------------------------------------------------------------------------
__global__ __launch_bounds__(256) void prep_w(const float* __restrict__ W,
                                              _Float16* __restrict__ WT) {
  __shared__ float t[64][65];
  const int tid = threadIdx.x;
  const int k0 = (blockIdx.x >> 3) * 64;
  const int n0 = (blockIdx.x & 7) * 64;
#pragma unroll
  for (int i = 0; i < 16; ++i) {
    int idx = i * 256 + tid;
    int kk = idx >> 6, nn = idx & 63;
    int n = n0 + nn;
    t[kk][nn] = (n < 511) ? W[(size_t)(k0 + kk) * 511 + n] : 0.f;
  }
  __syncthreads();
#pragma unroll
  for (int i = 0; i < 16; ++i) {
    int idx = i * 256 + tid;
    int nn = idx >> 6, kk = idx & 63;
    WT[(size_t)(n0 + nn) * 1024 + k0 + kk] = (_Float16)t[kk][nn];
  }
}

// ---------------------------------------------------------------------------
// Kernel 2 (FUSED, r13 verbatim — measured best, 47.0us total):
// 64 rows x full 512 cols per block -> 64x10 out, no P round-trip.
// GEMM: 1024 threads (16 waves 2Mx8N), BK=64, counted vmcnt(4),
// A reg-staged by threads 0..511 (f32 -> cvt_pkrtz f16 -> 16B ds_write),
// B via global_load_lds (pre-swizzled source), raw s_barrier pairs.
// Tree: sigmoid -> P in LDS (stride 520) -> tree + leaf MFMA -> out.
// ---------------------------------------------------------------------------
__global__ __launch_bounds__(1024, 1) void gemm_tree(const float* __restrict__ X,
                                                     const _Float16* __restrict__ WT,
                                                     const float* __restrict__ bvec,
                                                     const float* __restrict__ LL,
                                                     float* __restrict__ out) {
  __shared__ _Float16 ldsB[2][512 * 64];   // 128 KB; reused as plds+red after K-loop
  __shared__ _Float16 ldsA[2][64 * 64];    // 16 KB

  const int tid = threadIdx.x;            // 0..1023
  const int lane = tid & 63;
  const int w = tid >> 6;                 // 0..15
  const int wr = w >> 3, wc = w & 7;      // 2(M) x 8(N)
  const int l16 = lane & 15;
  const int g = lane >> 4;
  const int rbase = blockIdx.x * 64;

  // A staging (threads 0..511): row = tid>>3, 8 consecutive f32 per thread
  const bool doA = (tid < 512);
  const int arow = tid >> 3;
  const int aseg = tid & 7;
  const float* aSrc = X + (size_t)(rbase + arow) * 1024 + aseg * 8;
  const int awOff = arow * 64 + (aseg ^ (arow & 7)) * 8;  // swizzled 16B slot

  f32x4 acc[2][4];
#pragma unroll
  for (int i = 0; i < 2; ++i)
#pragma unroll
    for (int j = 0; j < 4; ++j) acc[i][j] = (f32x4)0.f;

  f32x4 aReg[2];

  auto issueA = [&](int kt) {
    if (doA) {
      const float* s = aSrc + kt * 64;
      aReg[0] = *(const f32x4*)(s);
      aReg[1] = *(const f32x4*)(s + 4);
    }
  };

  auto writeA = [&](int buf) {
    if (doA) {
      union { uint u[4]; f16x8 v; } c;
      c.u[0] = pk_f16(aReg[0][0], aReg[0][1]);
      c.u[1] = pk_f16(aReg[0][2], aReg[0][3]);
      c.u[2] = pk_f16(aReg[1][0], aReg[1][1]);
      c.u[3] = pk_f16(aReg[1][2], aReg[1][3]);
      *(f16x8*)&ldsA[buf][awOff] = c.v;
    }
  };

  auto issueB = [&](int buf, int kt) {
#pragma unroll
    for (int i = 0; i < 4; ++i) {
      int l = tid + 1024 * i;
      int c = l >> 3, gp = l & 7;
      int gs = gp ^ (c & 7);
      LDS16(WT + (size_t)c * 1024 + kt * 64 + gs * 8, &ldsB[buf][l * 8]);
    }
  };

  auto compute = [&](int buf) {
#pragma unroll
    for (int kk = 0; kk < 2; ++kk) {
      f16x8 b[4], a[2];
#pragma unroll
      for (int ni = 0; ni < 4; ++ni) {
        int c = wc * 64 + ni * 16 + l16;
        b[ni] = *(const f16x8*)&ldsB[buf][c * 64 + (((kk * 4 + g) ^ (c & 7)) * 8)];
      }
#pragma unroll
      for (int mi = 0; mi < 2; ++mi) {
        int r = wr * 32 + mi * 16 + l16;
        a[mi] = *(const f16x8*)&ldsA[buf][r * 64 + (((kk * 4 + g) ^ (r & 7)) * 8)];
      }
#pragma unroll
      for (int mi = 0; mi < 2; ++mi)
#pragma unroll
        for (int ni = 0; ni < 4; ++ni)
          acc[mi][ni] = __builtin_amdgcn_mfma_f32_16x16x32_f16(a[mi], b[ni], acc[mi][ni], 0, 0, 0);
    }
  };

  // prologue: B(0)[4], A(0)[2], B(1)[4] in flight
  issueB(0, 0);
  issueA(0);
  issueB(1, 1);

#pragma unroll
  for (int t = 0; t < 16; ++t) {
    const int buf = t & 1;
    if (t < 15) {
      asm volatile("s_waitcnt vmcnt(4)" ::: "memory");
    } else {
      asm volatile("s_waitcnt vmcnt(0)" ::: "memory");
    }
    __builtin_amdgcn_sched_barrier(0);
    writeA(buf);
    asm volatile("s_waitcnt lgkmcnt(0)" ::: "memory");
    __builtin_amdgcn_sched_barrier(0);
    __builtin_amdgcn_s_barrier();
    __builtin_amdgcn_sched_barrier(0);
    if (t + 1 < 16) issueA(t + 1);
    __builtin_amdgcn_sched_barrier(0);
    __builtin_amdgcn_s_setprio(1);
    compute(buf);
    __builtin_amdgcn_s_setprio(0);
    __builtin_amdgcn_sched_barrier(0);
    __builtin_amdgcn_s_barrier();                  // all waves done with buf
    if (t + 2 < 16) issueB(buf, t + 2);
  }
  // after final barrier: no wave touches ldsB as B again -> safe to reuse

  // ---- stage 2a: sigmoid -> P in LDS (padded stride 520) ----
  __half* plds = (__half*)&ldsB[0][0];                       // 64 x 520 = 66.5 KB
  f32x4* red = (f32x4*)((char*)&ldsB[0][0] + 68 * 1024);     // [4 rg][3][64] = 12 KB
#pragma unroll
  for (int mi = 0; mi < 2; ++mi) {
#pragma unroll
    for (int ni = 0; ni < 4; ++ni) {
      int gc = wc * 64 + ni * 16 + l16;
      float bias = (gc < 511) ? bvec[gc] : 0.f;
#pragma unroll
      for (int q = 0; q < 4; ++q) {
        int lr = wr * 32 + mi * 16 + g * 4 + q;   // local row 0..63
        float z = acc[mi][ni][q] + bias;
        float pv = 1.f / (1.f + __expf(-z));
        plds[lr * 520 + gc] = __float2half(pv);
      }
    }
  }
  __syncthreads();

  // ---- stage 2b: tree propagation + leaf MFMA ----
  // wave w: rg = w>>2 (16-row group), tw = w&3 (4 t-chunks t = tw*4+tt)
  const int rg = w >> 2, tw = w & 3;
  const int r = lane & 15;   // row within group; also LL col
  const int col = r;

  f16x8 bfr[4];
#pragma unroll
  for (int tt = 0; tt < 4; ++tt) {
    int t = tw * 4 + tt;
#pragma unroll
    for (int p = 0; p < 8; ++p) {
      int k0 = t * 32 + g * 8 + p;
      bfr[tt][p] = (col < 10) ? (_Float16)LL[k0 * 10 + col] : (_Float16)0.f;
    }
  }

  const __half* prow = &plds[(rg * 16 + r) * 520];
  f32x4 tacc = (f32x4)0.f;
#pragma unroll
  for (int tt = 0; tt < 4; ++tt) {
    const int t = tw * 4 + tt;
    const int L0 = g * 8 + 32 * t;
    float pref = 1.f;
#pragma unroll
    for (int k = 0; k < 6; ++k) {
      int node = L0 >> (9 - k);
      int bit = (L0 >> (8 - k)) & 1;
      float pv = __half2float(prow[(1 << k) - 1 + node]);
      pref *= bit ? pv : (1.f - pv);
    }
    float p6 = __half2float(prow[63 + (L0 >> 3)]);
    float p7a = __half2float(prow[127 + (L0 >> 2)]);
    float p7b = __half2float(prow[128 + (L0 >> 2)]);
    float p80 = __half2float(prow[255 + (L0 >> 1)]);
    float p81 = __half2float(prow[256 + (L0 >> 1)]);
    float p82 = __half2float(prow[257 + (L0 >> 1)]);
    float p83 = __half2float(prow[258 + (L0 >> 1)]);
    float u1 = pref * p6, u0 = pref - u1;
    float v01 = u0 * p7a, v00 = u0 - v01;
    float v11 = u1 * p7b, v10 = u1 - v11;
    float pr1 = v00 * p80, pr0 = v00 - pr1;
    float pr3 = v01 * p81, pr2 = v01 - pr3;
    float pr5 = v10 * p82, pr4 = v10 - pr5;
    float pr7 = v11 * p83, pr6 = v11 - pr7;
    f16x8 af;
    af[0] = (_Float16)pr0; af[1] = (_Float16)pr1;
    af[2] = (_Float16)pr2; af[3] = (_Float16)pr3;
    af[4] = (_Float16)pr4; af[5] = (_Float16)pr5;
    af[6] = (_Float16)pr6; af[7] = (_Float16)pr7;
    tacc = __builtin_amdgcn_mfma_f32_16x16x32_f16(af, bfr[tt], tacc, 0, 0, 0);
  }

  if (tw > 0) red[(rg * 3 + (tw - 1)) * 64 + lane] = tacc;
  __syncthreads();

  if (tw == 0 && col < 10) {
    f32x4 a1 = red[(rg * 3 + 0) * 64 + lane];
    f32x4 a2 = red[(rg * 3 + 1) * 64 + lane];
    f32x4 a3 = red[(rg * 3 + 2) * 64 + lane];
#pragma unroll
    for (int q = 0; q < 4; ++q)
      out[(size_t)(rbase + rg * 16 + g * 4 + q) * 10 + col] =
          tacc[q] + a1[q] + a2[q] + a3[q];
  }
}

// ---------------------------------------------------------------------------
extern "C" void kernel_launch(void* const* d_in, const int* in_sizes, int n_in,
                              void* d_out, int out_size, void* d_ws, size_t ws_size,
                              hipStream_t stream) {
  const float* X = (const float*)d_in[0];
  const float* W = (const float*)d_in[1];
  const float* bv = (const float*)d_in[2];
  const float* LL = (const float*)d_in[3];
  float* out = (float*)d_out;

  _Float16* WT = (_Float16*)d_ws;  // 1 MB

  prep_w<<<128, 256, 0, stream>>>(W, WT);
  gemm_tree<<<256, 1024, 0, stream>>>(X, WT, bv, LL, out);
}